// Round 11
// baseline (318.353 us; speedup 1.0000x reference)
//
#include <hip/hip_runtime.h>
#include <hip/hip_bf16.h>
#include <math.h>

#define NN 50000
#define FIN 128
#define FH 256        // H*C = 256 output features per layer
#define NE 800000
#define NG 256
#define ELLS 64       // ELL row stride (max degree incl self loop; Poisson(16) => P(>63) ~ 1e-20)
#define CSTRIDE 16    // cnt stride in ints: one counter per 64B line (atomic false-sharing fix)
#define NEG_SLOPE 0.2f
#define BN_EPS 1e-5f

typedef short bf16x8 __attribute__((ext_vector_type(8)));
typedef unsigned short u16x8 __attribute__((ext_vector_type(8)));
typedef unsigned long long u64x2 __attribute__((ext_vector_type(2)));
typedef float f32x4 __attribute__((ext_vector_type(4)));

__device__ __forceinline__ float lrelu(float x) { return x > 0.f ? x : NEG_SLOPE * x; }
__device__ __forceinline__ float bf2f(unsigned short u) { return __uint_as_float(((unsigned int)u) << 16); }
__device__ __forceinline__ unsigned short f2bf(float f) {
    __hip_bfloat16 b = __float2bfloat16(f);
    return *reinterpret_cast<unsigned short*>(&b);
}

// ---------------- prep: W transposes + ELL self-loop init, one launch ----------------
__global__ __launch_bounds__(256) void k_prep(const float* __restrict__ W1, unsigned short* __restrict__ W1t,
                                              const float* __restrict__ W2, unsigned short* __restrict__ W2t,
                                              int* __restrict__ cnt, int* __restrict__ colIdx) {
    int bid = blockIdx.x;
    if (bid < 384) {
        int o = bid * 256 + threadIdx.x;
        if (o < 256 * 128) {
            int c = o >> 7, k = o & 127;
            W1t[o] = f2bf(W1[(size_t)k * 256 + c]);
        } else {
            o -= 256 * 128;
            if (o < 256 * 256) {
                int c = o >> 8, k = o & 255;
                W2t[o] = f2bf(W2[(size_t)k * 256 + c]);
            }
        }
    } else {
        int i = (bid - 384) * 256 + threadIdx.x;
        if (i < NN) {
            cnt[(size_t)i * CSTRIDE] = 1;
            colIdx[(size_t)i * ELLS] = i;   // self loop first
        }
    }
}

// ---------------- GEMM + fused attention logits (+ fused ELL edge-fill HEAD blocks, MODE 0) ---
// C[M,256](bf16) = A[M,K] @ Bt[256,K]^T  (MFMA bf16, f32 accum)
// MODE 0: blocks [0,nFill) do ELL edge fill (atomics start immediately, overlap gemm);
//         blocks [nFill,nFill+nGemm) do the GEMM. MODE 1: all blocks GEMM; BN affine+relu staged.
// Epilogue: C staged through LDS -> 16B coalesced stores; attn logits from staged rows.
template<int MODE>
__global__ __launch_bounds__(256) void k_gemm(const float* __restrict__ Af, const unsigned short* __restrict__ Ab,
                                              const unsigned short* __restrict__ Bt,
                                              unsigned short* __restrict__ C,
                                              const float* __restrict__ attS, const float* __restrict__ attD,
                                              float* __restrict__ alsrc, float* __restrict__ aldst,
                                              const float* __restrict__ bnsum, const float* __restrict__ bnsq,
                                              const float* __restrict__ gamma, const float* __restrict__ beta,
                                              const int* __restrict__ eiFill, int* __restrict__ cntFill,
                                              int* __restrict__ colIdxFill, int nFill,
                                              int M, int K) {
    __shared__ short lds[10240];                 // As(5120) + Bs(5120); reused as 64x138 C-stage
    __shared__ float sAs_[128], sAd_[128];
    __shared__ float s_scale[MODE == 1 ? 256 : 1];
    __shared__ float s_shift[MODE == 1 ? 256 : 1];
    short* As = lds;
    short* Bs = lds + 5120;

    int bid = blockIdx.x;
    if (MODE == 0) {
        if (bid < nFill) {
            int i = bid * 256 + threadIdx.x;
            if (i < NE) {
                int s = eiFill[i], d = eiFill[NE + i];
                int pos = atomicAdd(&cntFill[(size_t)d * CSTRIDE], 1);
                if (pos < ELLS) colIdxFill[(size_t)d * ELLS + pos] = s;
            }
            return;
        }
        bid -= nFill;
    }
    int tid = threadIdx.x;
    int lane = tid & 63, wid = tid >> 6;
    int wr = wid >> 1, wc = wid & 1;
    int row0 = (bid >> 1) * 128, col0 = (bid & 1) * 128;

    if (tid < 128) {
        sAs_[tid] = attS[col0 + tid];
        sAd_[tid] = attD[col0 + tid];
    }
    if (MODE == 1) {
        const float invN = 1.f / (float)NN;
        float mean = bnsum[tid] * invN;
        float var  = bnsq[tid] * invN - mean * mean;
        float istd = rsqrtf(var + BN_EPS);
        float sc = gamma[tid] * istd;
        s_scale[tid] = sc;
        s_shift[tid] = beta[tid] - mean * sc;
        __syncthreads();
    }
    f32x4 acc[4][4];
#pragma unroll
    for (int m = 0; m < 4; ++m)
#pragma unroll
        for (int n = 0; n < 4; ++n) acc[m][n] = (f32x4){0.f, 0.f, 0.f, 0.f};

    int r = tid >> 2, seg = tid & 3;
    int koff = (lane >> 4) * 8;

    float4 qa0[2], qa1[2];
    bf16x8 qab[2];
    bf16x8 qb[2];
    const float4 zf4 = make_float4(0.f, 0.f, 0.f, 0.f);
    const bf16x8 zb8 = {0, 0, 0, 0, 0, 0, 0, 0};

#pragma unroll
    for (int j = 0; j < 2; ++j) {
        int grow = row0 + r + j * 64;
        if (MODE == 0) {
            if (grow < M) {
                const float* ap = Af + (size_t)grow * K + seg * 8;
                qa0[j] = *(const float4*)ap;
                qa1[j] = *((const float4*)ap + 1);
            } else { qa0[j] = zf4; qa1[j] = zf4; }
        } else {
            qab[j] = (grow < M) ? *(const bf16x8*)(Ab + (size_t)grow * K + seg * 8) : zb8;
        }
        qb[j] = *(const bf16x8*)(Bt + (size_t)(col0 + r + j * 64) * K + seg * 8);
    }

    for (int k0 = 0; k0 < K; k0 += 32) {
#pragma unroll
        for (int j = 0; j < 2; ++j) {
            int row = r + j * 64;
            bf16x8 va;
            if (MODE == 0) {
                va[0] = (short)f2bf(qa0[j].x); va[1] = (short)f2bf(qa0[j].y);
                va[2] = (short)f2bf(qa0[j].z); va[3] = (short)f2bf(qa0[j].w);
                va[4] = (short)f2bf(qa1[j].x); va[5] = (short)f2bf(qa1[j].y);
                va[6] = (short)f2bf(qa1[j].z); va[7] = (short)f2bf(qa1[j].w);
            } else {
                int cb = k0 + seg * 8;
#pragma unroll
                for (int k = 0; k < 8; ++k) {
                    float f = bf2f((unsigned short)qab[j][k]) * s_scale[cb + k] + s_shift[cb + k];
                    va[k] = (short)f2bf(fmaxf(f, 0.f));
                }
            }
            *(bf16x8*)&As[row * 40 + seg * 8] = va;
            *(bf16x8*)&Bs[row * 40 + seg * 8] = qb[j];
        }
        __syncthreads();
        int kn = k0 + 32;
        if (kn < K) {
#pragma unroll
            for (int j = 0; j < 2; ++j) {
                int grow = row0 + r + j * 64;
                if (MODE == 0) {
                    if (grow < M) {
                        const float* ap = Af + (size_t)grow * K + kn + seg * 8;
                        qa0[j] = *(const float4*)ap;
                        qa1[j] = *((const float4*)ap + 1);
                    } else { qa0[j] = zf4; qa1[j] = zf4; }
                } else {
                    qab[j] = (grow < M) ? *(const bf16x8*)(Ab + (size_t)grow * K + kn + seg * 8) : zb8;
                }
                qb[j] = *(const bf16x8*)(Bt + (size_t)(col0 + r + j * 64) * K + kn + seg * 8);
            }
        }
        bf16x8 af[4], bfr[4];
#pragma unroll
        for (int m = 0; m < 4; ++m)
            af[m] = *(const bf16x8*)&As[(wr * 64 + m * 16 + (lane & 15)) * 40 + koff];
#pragma unroll
        for (int n = 0; n < 4; ++n)
            bfr[n] = *(const bf16x8*)&Bs[(wc * 64 + n * 16 + (lane & 15)) * 40 + koff];
#pragma unroll
        for (int m = 0; m < 4; ++m)
#pragma unroll
            for (int n = 0; n < 4; ++n)
                acc[m][n] = __builtin_amdgcn_mfma_f32_16x16x32_bf16(af[m], bfr[n], acc[m][n], 0, 0, 0);
        __syncthreads();
    }

    // ---- epilogue: stage C tile through LDS in two 64-row halves ----
    const int CST = 138;   // shorts; 64*138 = 8832 <= 10240
#pragma unroll 1
    for (int hh = 0; hh < 2; ++hh) {
        if (wr == hh) {
#pragma unroll
            for (int m = 0; m < 4; ++m) {
                int rl = m * 16 + (lane >> 4) * 4;
#pragma unroll
                for (int n = 0; n < 4; ++n) {
                    int cl = wc * 64 + n * 16 + (lane & 15);
#pragma unroll
                    for (int j = 0; j < 4; ++j)
                        lds[(rl + j) * CST + cl] = (short)f2bf(acc[m][n][j]);
                }
            }
        }
        __syncthreads();
        int rl = tid >> 2, q = tid & 3;
        int grow = row0 + hh * 64 + rl;
        if (grow < M) {
            const short* cp = &lds[rl * CST + q * 32];
            bf16x8 v0 = *(const bf16x8*)(cp + 0);
            bf16x8 v1 = *(const bf16x8*)(cp + 8);
            bf16x8 v2 = *(const bf16x8*)(cp + 16);
            bf16x8 v3 = *(const bf16x8*)(cp + 24);
            unsigned short* op = C + (size_t)grow * 256 + col0 + q * 32;
            *(bf16x8*)(op + 0)  = v0;
            *(bf16x8*)(op + 8)  = v1;
            *(bf16x8*)(op + 16) = v2;
            *(bf16x8*)(op + 24) = v3;
            float ps = 0.f, pd = 0.f;
            const float* aS = &sAs_[q * 32];
            const float* aD = &sAd_[q * 32];
#pragma unroll
            for (int k = 0; k < 8; ++k) {
                float f0 = bf2f((unsigned short)v0[k]);
                float f1 = bf2f((unsigned short)v1[k]);
                float f2 = bf2f((unsigned short)v2[k]);
                float f3 = bf2f((unsigned short)v3[k]);
                ps += f0 * aS[k] + f1 * aS[k + 8] + f2 * aS[k + 16] + f3 * aS[k + 24];
                pd += f0 * aD[k] + f1 * aD[k + 8] + f2 * aD[k + 16] + f3 * aD[k + 24];
            }
            ps += __shfl_xor(ps, 1);
            pd += __shfl_xor(pd, 1);
            if ((q & 1) == 0) {
                int head = (col0 >> 6) + (q >> 1);
                alsrc[grow * 4 + head] = ps;
                aldst[grow * 4 + head] = pd;
            }
        }
        __syncthreads();
    }
}

// ---------------- GAT aggregation: 2 nodes per wave (32-lane halves), ELL, 2 edges in flight ---
__global__ __launch_bounds__(256) void k_gat_agg(const int* __restrict__ cnt, const int* __restrict__ colIdx,
    const float* __restrict__ alsrc, const float* __restrict__ aldst, const unsigned short* __restrict__ h,
    const float* __restrict__ bias, unsigned short* __restrict__ outb, int relu_nt, int n) {
    __shared__ float ex_s[4][2][32][4];
    __shared__ int   src_s[4][2][32];
    int wave = threadIdx.x >> 6, lane = threadIdx.x & 63;
    int half = lane >> 5, hlane = lane & 31;
    int node = blockIdx.x * 8 + wave * 2 + half;   // grid = NN/8 exactly
    int deg = min(cnt[(size_t)node * CSTRIDE], ELLS);
    const int* crow = colIdx + (size_t)node * ELLS;
    int hf = hlane >> 3;
    float4 ad = *(const float4*)(aldst + (size_t)node * 4);
    float m0 = -1e30f, m1 = -1e30f, m2 = -1e30f, m3 = -1e30f;
    float d0 = 0.f, d1 = 0.f, d2 = 0.f, d3 = 0.f;
    float acc[8];
#pragma unroll
    for (int k = 0; k < 8; ++k) acc[k] = 0.f;

    for (int base = 0; base < deg; base += 32) {
        int cnt32 = min(32, deg - base);
        int src = node;
        float e0 = -1e30f, e1 = -1e30f, e2 = -1e30f, e3 = -1e30f;
        if (hlane < cnt32) {
            src = crow[base + hlane];
            float4 as = *(const float4*)(alsrc + (size_t)src * 4);
            e0 = lrelu(as.x + ad.x);
            e1 = lrelu(as.y + ad.y);
            e2 = lrelu(as.z + ad.z);
            e3 = lrelu(as.w + ad.w);
        }
        float c0 = e0, c1 = e1, c2 = e2, c3 = e3;
#pragma unroll
        for (int off = 16; off > 0; off >>= 1) {
            c0 = fmaxf(c0, __shfl_xor(c0, off));
            c1 = fmaxf(c1, __shfl_xor(c1, off));
            c2 = fmaxf(c2, __shfl_xor(c2, off));
            c3 = fmaxf(c3, __shfl_xor(c3, off));
        }
        float nm0 = fmaxf(m0, c0), nm1 = fmaxf(m1, c1), nm2 = fmaxf(m2, c2), nm3 = fmaxf(m3, c3);
        float sc0 = __expf(m0 - nm0), sc1 = __expf(m1 - nm1), sc2 = __expf(m2 - nm2), sc3 = __expf(m3 - nm3);
        float x0 = __expf(e0 - nm0), x1 = __expf(e1 - nm1), x2 = __expf(e2 - nm2), x3 = __expf(e3 - nm3);
        float s0 = x0, s1 = x1, s2 = x2, s3 = x3;
#pragma unroll
        for (int off = 16; off > 0; off >>= 1) {
            s0 += __shfl_xor(s0, off);
            s1 += __shfl_xor(s1, off);
            s2 += __shfl_xor(s2, off);
            s3 += __shfl_xor(s3, off);
        }
        d0 = d0 * sc0 + s0; d1 = d1 * sc1 + s1; d2 = d2 * sc2 + s2; d3 = d3 * sc3 + s3;
        m0 = nm0; m1 = nm1; m2 = nm2; m3 = nm3;
        float scl = (hf == 0) ? sc0 : (hf == 1) ? sc1 : (hf == 2) ? sc2 : sc3;
#pragma unroll
        for (int k = 0; k < 8; ++k) acc[k] *= scl;
        ex_s[wave][half][hlane][0] = x0; ex_s[wave][half][hlane][1] = x1;
        ex_s[wave][half][hlane][2] = x2; ex_s[wave][half][hlane][3] = x3;
        src_s[wave][half][hlane] = src;
        for (int j = 0; j < cnt32; j += 2) {
            float w0 = ex_s[wave][half][j][hf];
            bf16x8 h0 = *(const bf16x8*)(h + (size_t)src_s[wave][half][j] * 256 + hlane * 8);
            float w1 = 0.f;
            bf16x8 h1 = {0, 0, 0, 0, 0, 0, 0, 0};
            if (j + 1 < cnt32) {
                w1 = ex_s[wave][half][j + 1][hf];
                h1 = *(const bf16x8*)(h + (size_t)src_s[wave][half][j + 1] * 256 + hlane * 8);
            }
#pragma unroll
            for (int k = 0; k < 8; ++k)
                acc[k] = fmaf(w0, bf2f((unsigned short)h0[k]), acc[k]);
#pragma unroll
            for (int k = 0; k < 8; ++k)
                acc[k] = fmaf(w1, bf2f((unsigned short)h1[k]), acc[k]);
        }
    }

    float dd = (hf == 0) ? d0 : (hf == 1) ? d1 : (hf == 2) ? d2 : d3;
    float inv = 1.f / (dd + 1e-16f);
    float4 b0 = *(const float4*)(bias + hlane * 8);
    float4 b1 = *(const float4*)(bias + hlane * 8 + 4);
    float o[8];
    o[0] = acc[0] * inv + b0.x; o[1] = acc[1] * inv + b0.y;
    o[2] = acc[2] * inv + b0.z; o[3] = acc[3] * inv + b0.w;
    o[4] = acc[4] * inv + b1.x; o[5] = acc[5] * inv + b1.y;
    o[6] = acc[6] * inv + b1.z; o[7] = acc[7] * inv + b1.w;
    u16x8 ob;
    if (relu_nt) {
#pragma unroll
        for (int k = 0; k < 8; ++k) ob[k] = f2bf(fmaxf(o[k], 0.f));
        u64x2 w = *(u64x2*)&ob;
        __builtin_nontemporal_store(w, (u64x2*)(outb + (size_t)node * 256 + hlane * 8));
    } else {
#pragma unroll
        for (int k = 0; k < 8; ++k) ob[k] = f2bf(o[k]);
        *(u64x2*)(outb + (size_t)node * 256 + hlane * 8) = *(u64x2*)&ob;
    }
}

// ---------------- BatchNorm stats ----------------
__global__ __launch_bounds__(256) void k_bn_stats(const unsigned short* __restrict__ xin, float* bnsum, float* bnsq) {
    int t = threadIdx.x;
    int r0 = blockIdx.x * 250;
    float s = 0.f, q = 0.f;
    for (int r = r0; r < r0 + 250; ++r) {
        float v = bf2f(xin[(size_t)r * 256 + t]);
        s += v; q += v * v;
    }
    atomicAdd(&bnsum[t], s);
    atomicAdd(&bnsq[t], q);
}

// ---------------- pooling: one block per group, binary search, no atomics ----------------
__global__ __launch_bounds__(512) void k_pool(const unsigned short* __restrict__ x1pre,
    const unsigned short* __restrict__ x2b, const int* __restrict__ batch,
    const float* __restrict__ bnsum, const float* __restrict__ bnsq,
    const float* __restrict__ gamma, const float* __restrict__ beta,
    float* __restrict__ out) {
    int g = blockIdx.x;
    __shared__ int sLo, sHi;
    if (threadIdx.x == 0) {
        int lo = 0, hi = NN;
        while (lo < hi) { int m = (lo + hi) >> 1; if (batch[m] < g) lo = m + 1; else hi = m; }
        sLo = lo;
    }
    if (threadIdx.x == 1) {
        int lo = 0, hi = NN;
        while (lo < hi) { int m = (lo + hi) >> 1; if (batch[m] < g + 1) lo = m + 1; else hi = m; }
        sHi = lo;
    }
    __syncthreads();
    int lo = sLo, hi = sHi, cnt = hi - lo;
    int t = threadIdx.x;
    bool first = t < 256;
    int f = first ? t : t - 256;
    const unsigned short* src = first ? x1pre : x2b;
    float sc = 1.f, sh = 0.f;
    if (first) {
        const float invN = 1.f / (float)NN;
        float mean = bnsum[f] * invN;
        float var  = bnsq[f] * invN - mean * mean;
        float istd = rsqrtf(var + BN_EPS);
        sc = gamma[f] * istd;
        sh = beta[f] - mean * sc;
    }
    float s = 0.f, mx = 0.f;
    int r = lo;
    for (; r + 1 < hi; r += 2) {
        float va = bf2f(src[(size_t)r * 256 + f]);
        float vb = bf2f(src[(size_t)(r + 1) * 256 + f]);
        if (first) {
            va = fmaxf(va * sc + sh, 0.f);
            vb = fmaxf(vb * sc + sh, 0.f);
        }
        s += va + vb;
        mx = fmaxf(mx, fmaxf(va, vb));
    }
    if (r < hi) {
        float va = bf2f(src[(size_t)r * 256 + f]);
        if (first) va = fmaxf(va * sc + sh, 0.f);
        s += va; mx = fmaxf(mx, va);
    }
    float mean = (cnt > 0) ? s / (float)cnt : 0.f;
    int off = first ? 0 : 256;
    out[g * 1024 + off + f] = mean;
    out[g * 1024 + 512 + off + f] = mx;
}

extern "C" void kernel_launch(void* const* d_in, const int* in_sizes, int n_in,
                              void* d_out, int out_size, void* d_ws, size_t ws_size,
                              hipStream_t stream) {
    const float* x     = (const float*)d_in[0];
    const int*   ei    = (const int*)d_in[1];
    const int*   batch = (const int*)d_in[2];
    const float* W1    = (const float*)d_in[3];
    const float* asrc1 = (const float*)d_in[4];
    const float* adst1 = (const float*)d_in[5];
    const float* b1    = (const float*)d_in[6];
    const float* gamma = (const float*)d_in[7];
    const float* beta  = (const float*)d_in[8];
    const float* W2    = (const float*)d_in[9];
    const float* asrc2 = (const float*)d_in[10];
    const float* adst2 = (const float*)d_in[11];
    const float* b2    = (const float*)d_in[12];
    float* out = (float*)d_out;

    char* p = (char*)d_ws;
    auto alloc = [&](size_t bytes) -> void* {
        void* r = (void*)p;
        p += (bytes + 255) & ~(size_t)255;
        return r;
    };
    unsigned short* hb    = (unsigned short*)alloc((size_t)NN * 256 * 2);
    unsigned short* x1pre = (unsigned short*)alloc((size_t)NN * 256 * 2);
    unsigned short* x2b   = (unsigned short*)alloc((size_t)NN * 256 * 2);
    unsigned short* W1t   = (unsigned short*)alloc((size_t)256 * 128 * 2);
    unsigned short* W2t   = (unsigned short*)alloc((size_t)256 * 256 * 2);
    float* alsrc = (float*)alloc((size_t)NN * 4 * 4);
    float* aldst = (float*)alloc((size_t)NN * 4 * 4);
    float* bnsum = (float*)alloc(256 * 4);
    float* bnsq  = (float*)alloc(256 * 4);       // contiguous with bnsum (one 2 KB memset)
    int*   cnt   = (int*)alloc((size_t)NN * CSTRIDE * 4);   // 3.2 MB, 1 counter per 64B line
    int*   colIdx = (int*)alloc((size_t)NN * ELLS * 4);     // ELL, 12.8 MB

    (void)hipMemsetAsync(bnsum, 0, 2 * 1024, stream);

    const int nFill = (NE + 255) / 256;           // 3125
    const int nGemm = 2 * ((NN + 127) / 128);     // 782

    // prep: W transposes + ELL self-loop/cnt init (cnt needs no memset)
    k_prep<<<384 + 196, 256, 0, stream>>>(W1, W1t, W2, W2t, cnt, colIdx);

    // layer 1: ELL edge fill (head blocks, overlaps) + GEMM + fused attn logits
    k_gemm<0><<<nFill + nGemm, 256, 0, stream>>>(x, nullptr, W1t, hb, asrc1, adst1, alsrc, aldst,
                                                 nullptr, nullptr, nullptr, nullptr,
                                                 ei, cnt, colIdx, nFill, NN, 128);
    k_gat_agg<<<NN / 8, 256, 0, stream>>>(cnt, colIdx, alsrc, aldst, hb, b1, x1pre, 0, NN);
    k_bn_stats<<<200, 256, 0, stream>>>(x1pre, bnsum, bnsq);

    // layer 2
    k_gemm<1><<<nGemm, 256, 0, stream>>>(nullptr, x1pre, W2t, hb, asrc2, adst2, alsrc, aldst,
                                         bnsum, bnsq, gamma, beta,
                                         nullptr, nullptr, nullptr, 0, NN, 256);
    k_gat_agg<<<NN / 8, 256, 0, stream>>>(cnt, colIdx, alsrc, aldst, hb, b2, x2b, 1, NN);

    // pooling
    k_pool<<<NG, 512, 0, stream>>>(x1pre, x2b, batch, bnsum, bnsq, gamma, beta, out);
}

// Round 12
// 302.835 us; speedup vs baseline: 1.0512x; 1.0512x over previous
//
#include <hip/hip_runtime.h>
#include <hip/hip_bf16.h>
#include <math.h>

#define NN 50000
#define FIN 128
#define FH 256        // H*C = 256 output features per layer
#define NE 800000
#define NG 256
#define ELLS 64       // ELL row stride (max degree incl self loop; Poisson(16) => P(>63) ~ 1e-20)
#define NEG_SLOPE 0.2f
#define BN_EPS 1e-5f

typedef short bf16x8 __attribute__((ext_vector_type(8)));
typedef unsigned short u16x8 __attribute__((ext_vector_type(8)));
typedef unsigned long long u64x2 __attribute__((ext_vector_type(2)));
typedef float f32x4 __attribute__((ext_vector_type(4)));

__device__ __forceinline__ float lrelu(float x) { return x > 0.f ? x : NEG_SLOPE * x; }
__device__ __forceinline__ float bf2f(unsigned short u) { return __uint_as_float(((unsigned int)u) << 16); }
__device__ __forceinline__ unsigned short f2bf(float f) {
    __hip_bfloat16 b = __float2bfloat16(f);
    return *reinterpret_cast<unsigned short*>(&b);
}

// ---------------- prep: W transposes + ELL self-loop init, one launch ----------------
__global__ __launch_bounds__(256) void k_prep(const float* __restrict__ W1, unsigned short* __restrict__ W1t,
                                              const float* __restrict__ W2, unsigned short* __restrict__ W2t,
                                              int* __restrict__ cnt, int* __restrict__ colIdx) {
    int bid = blockIdx.x;
    if (bid < 384) {
        int o = bid * 256 + threadIdx.x;
        if (o < 256 * 128) {
            int c = o >> 7, k = o & 127;
            W1t[o] = f2bf(W1[(size_t)k * 256 + c]);
        } else {
            o -= 256 * 128;
            if (o < 256 * 256) {
                int c = o >> 8, k = o & 255;
                W2t[o] = f2bf(W2[(size_t)k * 256 + c]);
            }
        }
    } else {
        int i = (bid - 384) * 256 + threadIdx.x;
        if (i < NN) {
            cnt[i] = 1;
            colIdx[(size_t)i * ELLS] = i;   // self loop first
        }
    }
}

// ---------------- ELL edge fill: standalone, 4 edges per thread (ILP) ----------------
// T = gridDim*256 threads; thread t handles edges t, t+T, t+2T, t+3T.
__global__ __launch_bounds__(256) void k_fill(const int* __restrict__ ei, int* __restrict__ cnt,
                                              int* __restrict__ colIdx) {
    int T = gridDim.x * 256;
    int t = blockIdx.x * 256 + threadIdx.x;
    int e0 = t, e1 = t + T, e2 = t + 2 * T, e3 = t + 3 * T;
    int s0 = 0, s1 = 0, s2 = 0, s3 = 0, d0 = -1, d1 = -1, d2 = -1, d3 = -1;
    if (e0 < NE) { s0 = ei[e0]; d0 = ei[NE + e0]; }
    if (e1 < NE) { s1 = ei[e1]; d1 = ei[NE + e1]; }
    if (e2 < NE) { s2 = ei[e2]; d2 = ei[NE + e2]; }
    if (e3 < NE) { s3 = ei[e3]; d3 = ei[NE + e3]; }
    int p0 = 0, p1 = 0, p2 = 0, p3 = 0;
    if (d0 >= 0) p0 = atomicAdd(&cnt[d0], 1);
    if (d1 >= 0) p1 = atomicAdd(&cnt[d1], 1);
    if (d2 >= 0) p2 = atomicAdd(&cnt[d2], 1);
    if (d3 >= 0) p3 = atomicAdd(&cnt[d3], 1);
    if (d0 >= 0 && p0 < ELLS) colIdx[(size_t)d0 * ELLS + p0] = s0;
    if (d1 >= 0 && p1 < ELLS) colIdx[(size_t)d1 * ELLS + p1] = s1;
    if (d2 >= 0 && p2 < ELLS) colIdx[(size_t)d2 * ELLS + p2] = s2;
    if (d3 >= 0 && p3 < ELLS) colIdx[(size_t)d3 * ELLS + p3] = s3;
}

// ---------------- GEMM + fused attention logits ----------------
// C[M,256](bf16) = A[M,K] @ Bt[256,K]^T  (MFMA bf16, f32 accum)
// MODE 0: A f32. MODE 1: A bf16 pre-BN, staging applies BN affine+relu.
// Epilogue: C staged through LDS -> 16B coalesced stores; attn logits from staged rows.
template<int MODE>
__global__ __launch_bounds__(256) void k_gemm(const float* __restrict__ Af, const unsigned short* __restrict__ Ab,
                                              const unsigned short* __restrict__ Bt,
                                              unsigned short* __restrict__ C,
                                              const float* __restrict__ attS, const float* __restrict__ attD,
                                              float* __restrict__ alsrc, float* __restrict__ aldst,
                                              const float* __restrict__ bnsum, const float* __restrict__ bnsq,
                                              const float* __restrict__ gamma, const float* __restrict__ beta,
                                              int M, int K) {
    __shared__ short lds[10240];                 // As(5120) + Bs(5120); reused as 64x138 C-stage
    __shared__ float sAs_[128], sAd_[128];
    __shared__ float s_scale[MODE == 1 ? 256 : 1];
    __shared__ float s_shift[MODE == 1 ? 256 : 1];
    short* As = lds;
    short* Bs = lds + 5120;

    int bid = blockIdx.x;
    int tid = threadIdx.x;
    int lane = tid & 63, wid = tid >> 6;
    int wr = wid >> 1, wc = wid & 1;
    int row0 = (bid >> 1) * 128, col0 = (bid & 1) * 128;

    if (tid < 128) {
        sAs_[tid] = attS[col0 + tid];
        sAd_[tid] = attD[col0 + tid];
    }
    if (MODE == 1) {
        const float invN = 1.f / (float)NN;
        float mean = bnsum[tid] * invN;
        float var  = bnsq[tid] * invN - mean * mean;
        float istd = rsqrtf(var + BN_EPS);
        float sc = gamma[tid] * istd;
        s_scale[tid] = sc;
        s_shift[tid] = beta[tid] - mean * sc;
        __syncthreads();
    }
    f32x4 acc[4][4];
#pragma unroll
    for (int m = 0; m < 4; ++m)
#pragma unroll
        for (int n = 0; n < 4; ++n) acc[m][n] = (f32x4){0.f, 0.f, 0.f, 0.f};

    int r = tid >> 2, seg = tid & 3;
    int koff = (lane >> 4) * 8;

    float4 qa0[2], qa1[2];
    bf16x8 qab[2];
    bf16x8 qb[2];
    const float4 zf4 = make_float4(0.f, 0.f, 0.f, 0.f);
    const bf16x8 zb8 = {0, 0, 0, 0, 0, 0, 0, 0};

#pragma unroll
    for (int j = 0; j < 2; ++j) {
        int grow = row0 + r + j * 64;
        if (MODE == 0) {
            if (grow < M) {
                const float* ap = Af + (size_t)grow * K + seg * 8;
                qa0[j] = *(const float4*)ap;
                qa1[j] = *((const float4*)ap + 1);
            } else { qa0[j] = zf4; qa1[j] = zf4; }
        } else {
            qab[j] = (grow < M) ? *(const bf16x8*)(Ab + (size_t)grow * K + seg * 8) : zb8;
        }
        qb[j] = *(const bf16x8*)(Bt + (size_t)(col0 + r + j * 64) * K + seg * 8);
    }

    for (int k0 = 0; k0 < K; k0 += 32) {
#pragma unroll
        for (int j = 0; j < 2; ++j) {
            int row = r + j * 64;
            bf16x8 va;
            if (MODE == 0) {
                va[0] = (short)f2bf(qa0[j].x); va[1] = (short)f2bf(qa0[j].y);
                va[2] = (short)f2bf(qa0[j].z); va[3] = (short)f2bf(qa0[j].w);
                va[4] = (short)f2bf(qa1[j].x); va[5] = (short)f2bf(qa1[j].y);
                va[6] = (short)f2bf(qa1[j].z); va[7] = (short)f2bf(qa1[j].w);
            } else {
                int cb = k0 + seg * 8;
#pragma unroll
                for (int k = 0; k < 8; ++k) {
                    float f = bf2f((unsigned short)qab[j][k]) * s_scale[cb + k] + s_shift[cb + k];
                    va[k] = (short)f2bf(fmaxf(f, 0.f));
                }
            }
            *(bf16x8*)&As[row * 40 + seg * 8] = va;
            *(bf16x8*)&Bs[row * 40 + seg * 8] = qb[j];
        }
        __syncthreads();
        int kn = k0 + 32;
        if (kn < K) {
#pragma unroll
            for (int j = 0; j < 2; ++j) {
                int grow = row0 + r + j * 64;
                if (MODE == 0) {
                    if (grow < M) {
                        const float* ap = Af + (size_t)grow * K + kn + seg * 8;
                        qa0[j] = *(const float4*)ap;
                        qa1[j] = *((const float4*)ap + 1);
                    } else { qa0[j] = zf4; qa1[j] = zf4; }
                } else {
                    qab[j] = (grow < M) ? *(const bf16x8*)(Ab + (size_t)grow * K + kn + seg * 8) : zb8;
                }
                qb[j] = *(const bf16x8*)(Bt + (size_t)(col0 + r + j * 64) * K + kn + seg * 8);
            }
        }
        bf16x8 af[4], bfr[4];
#pragma unroll
        for (int m = 0; m < 4; ++m)
            af[m] = *(const bf16x8*)&As[(wr * 64 + m * 16 + (lane & 15)) * 40 + koff];
#pragma unroll
        for (int n = 0; n < 4; ++n)
            bfr[n] = *(const bf16x8*)&Bs[(wc * 64 + n * 16 + (lane & 15)) * 40 + koff];
#pragma unroll
        for (int m = 0; m < 4; ++m)
#pragma unroll
            for (int n = 0; n < 4; ++n)
                acc[m][n] = __builtin_amdgcn_mfma_f32_16x16x32_bf16(af[m], bfr[n], acc[m][n], 0, 0, 0);
        __syncthreads();
    }

    // ---- epilogue: stage C tile through LDS in two 64-row halves ----
    const int CST = 138;   // shorts; 64*138 = 8832 <= 10240
#pragma unroll 1
    for (int hh = 0; hh < 2; ++hh) {
        if (wr == hh) {
#pragma unroll
            for (int m = 0; m < 4; ++m) {
                int rl = m * 16 + (lane >> 4) * 4;
#pragma unroll
                for (int n = 0; n < 4; ++n) {
                    int cl = wc * 64 + n * 16 + (lane & 15);
#pragma unroll
                    for (int j = 0; j < 4; ++j)
                        lds[(rl + j) * CST + cl] = (short)f2bf(acc[m][n][j]);
                }
            }
        }
        __syncthreads();
        int rl = tid >> 2, q = tid & 3;
        int grow = row0 + hh * 64 + rl;
        if (grow < M) {
            const short* cp = &lds[rl * CST + q * 32];
            bf16x8 v0 = *(const bf16x8*)(cp + 0);
            bf16x8 v1 = *(const bf16x8*)(cp + 8);
            bf16x8 v2 = *(const bf16x8*)(cp + 16);
            bf16x8 v3 = *(const bf16x8*)(cp + 24);
            unsigned short* op = C + (size_t)grow * 256 + col0 + q * 32;
            *(bf16x8*)(op + 0)  = v0;
            *(bf16x8*)(op + 8)  = v1;
            *(bf16x8*)(op + 16) = v2;
            *(bf16x8*)(op + 24) = v3;
            float ps = 0.f, pd = 0.f;
            const float* aS = &sAs_[q * 32];
            const float* aD = &sAd_[q * 32];
#pragma unroll
            for (int k = 0; k < 8; ++k) {
                float f0 = bf2f((unsigned short)v0[k]);
                float f1 = bf2f((unsigned short)v1[k]);
                float f2 = bf2f((unsigned short)v2[k]);
                float f3 = bf2f((unsigned short)v3[k]);
                ps += f0 * aS[k] + f1 * aS[k + 8] + f2 * aS[k + 16] + f3 * aS[k + 24];
                pd += f0 * aD[k] + f1 * aD[k + 8] + f2 * aD[k + 16] + f3 * aD[k + 24];
            }
            ps += __shfl_xor(ps, 1);
            pd += __shfl_xor(pd, 1);
            if ((q & 1) == 0) {
                int head = (col0 >> 6) + (q >> 1);
                alsrc[grow * 4 + head] = ps;
                aldst[grow * 4 + head] = pd;
            }
        }
        __syncthreads();
    }
}

// ---------------- GAT aggregation: 2 nodes per wave (32-lane halves), ELL, 2 edges in flight ---
__global__ __launch_bounds__(256) void k_gat_agg(const int* __restrict__ cnt, const int* __restrict__ colIdx,
    const float* __restrict__ alsrc, const float* __restrict__ aldst, const unsigned short* __restrict__ h,
    const float* __restrict__ bias, unsigned short* __restrict__ outb, int relu_nt, int n) {
    __shared__ float ex_s[4][2][32][4];
    __shared__ int   src_s[4][2][32];
    int wave = threadIdx.x >> 6, lane = threadIdx.x & 63;
    int half = lane >> 5, hlane = lane & 31;
    int node = blockIdx.x * 8 + wave * 2 + half;   // grid = NN/8 exactly
    int deg = min(cnt[node], ELLS);
    const int* crow = colIdx + (size_t)node * ELLS;
    int hf = hlane >> 3;
    float4 ad = *(const float4*)(aldst + (size_t)node * 4);
    float m0 = -1e30f, m1 = -1e30f, m2 = -1e30f, m3 = -1e30f;
    float d0 = 0.f, d1 = 0.f, d2 = 0.f, d3 = 0.f;
    float acc[8];
#pragma unroll
    for (int k = 0; k < 8; ++k) acc[k] = 0.f;

    for (int base = 0; base < deg; base += 32) {
        int cnt32 = min(32, deg - base);
        int src = node;
        float e0 = -1e30f, e1 = -1e30f, e2 = -1e30f, e3 = -1e30f;
        if (hlane < cnt32) {
            src = crow[base + hlane];
            float4 as = *(const float4*)(alsrc + (size_t)src * 4);
            e0 = lrelu(as.x + ad.x);
            e1 = lrelu(as.y + ad.y);
            e2 = lrelu(as.z + ad.z);
            e3 = lrelu(as.w + ad.w);
        }
        float c0 = e0, c1 = e1, c2 = e2, c3 = e3;
#pragma unroll
        for (int off = 16; off > 0; off >>= 1) {
            c0 = fmaxf(c0, __shfl_xor(c0, off));
            c1 = fmaxf(c1, __shfl_xor(c1, off));
            c2 = fmaxf(c2, __shfl_xor(c2, off));
            c3 = fmaxf(c3, __shfl_xor(c3, off));
        }
        float nm0 = fmaxf(m0, c0), nm1 = fmaxf(m1, c1), nm2 = fmaxf(m2, c2), nm3 = fmaxf(m3, c3);
        float sc0 = __expf(m0 - nm0), sc1 = __expf(m1 - nm1), sc2 = __expf(m2 - nm2), sc3 = __expf(m3 - nm3);
        float x0 = __expf(e0 - nm0), x1 = __expf(e1 - nm1), x2 = __expf(e2 - nm2), x3 = __expf(e3 - nm3);
        float s0 = x0, s1 = x1, s2 = x2, s3 = x3;
#pragma unroll
        for (int off = 16; off > 0; off >>= 1) {
            s0 += __shfl_xor(s0, off);
            s1 += __shfl_xor(s1, off);
            s2 += __shfl_xor(s2, off);
            s3 += __shfl_xor(s3, off);
        }
        d0 = d0 * sc0 + s0; d1 = d1 * sc1 + s1; d2 = d2 * sc2 + s2; d3 = d3 * sc3 + s3;
        m0 = nm0; m1 = nm1; m2 = nm2; m3 = nm3;
        float scl = (hf == 0) ? sc0 : (hf == 1) ? sc1 : (hf == 2) ? sc2 : sc3;
#pragma unroll
        for (int k = 0; k < 8; ++k) acc[k] *= scl;
        ex_s[wave][half][hlane][0] = x0; ex_s[wave][half][hlane][1] = x1;
        ex_s[wave][half][hlane][2] = x2; ex_s[wave][half][hlane][3] = x3;
        src_s[wave][half][hlane] = src;
        for (int j = 0; j < cnt32; j += 2) {
            float w0 = ex_s[wave][half][j][hf];
            bf16x8 h0 = *(const bf16x8*)(h + (size_t)src_s[wave][half][j] * 256 + hlane * 8);
            float w1 = 0.f;
            bf16x8 h1 = {0, 0, 0, 0, 0, 0, 0, 0};
            if (j + 1 < cnt32) {
                w1 = ex_s[wave][half][j + 1][hf];
                h1 = *(const bf16x8*)(h + (size_t)src_s[wave][half][j + 1] * 256 + hlane * 8);
            }
#pragma unroll
            for (int k = 0; k < 8; ++k)
                acc[k] = fmaf(w0, bf2f((unsigned short)h0[k]), acc[k]);
#pragma unroll
            for (int k = 0; k < 8; ++k)
                acc[k] = fmaf(w1, bf2f((unsigned short)h1[k]), acc[k]);
        }
    }

    float dd = (hf == 0) ? d0 : (hf == 1) ? d1 : (hf == 2) ? d2 : d3;
    float inv = 1.f / (dd + 1e-16f);
    float4 b0 = *(const float4*)(bias + hlane * 8);
    float4 b1 = *(const float4*)(bias + hlane * 8 + 4);
    float o[8];
    o[0] = acc[0] * inv + b0.x; o[1] = acc[1] * inv + b0.y;
    o[2] = acc[2] * inv + b0.z; o[3] = acc[3] * inv + b0.w;
    o[4] = acc[4] * inv + b1.x; o[5] = acc[5] * inv + b1.y;
    o[6] = acc[6] * inv + b1.z; o[7] = acc[7] * inv + b1.w;
    u16x8 ob;
    if (relu_nt) {
#pragma unroll
        for (int k = 0; k < 8; ++k) ob[k] = f2bf(fmaxf(o[k], 0.f));
        u64x2 w = *(u64x2*)&ob;
        __builtin_nontemporal_store(w, (u64x2*)(outb + (size_t)node * 256 + hlane * 8));
    } else {
#pragma unroll
        for (int k = 0; k < 8; ++k) ob[k] = f2bf(o[k]);
        *(u64x2*)(outb + (size_t)node * 256 + hlane * 8) = *(u64x2*)&ob;
    }
}

// ---------------- BatchNorm stats ----------------
__global__ __launch_bounds__(256) void k_bn_stats(const unsigned short* __restrict__ xin, float* bnsum, float* bnsq) {
    int t = threadIdx.x;
    int r0 = blockIdx.x * 250;
    float s = 0.f, q = 0.f;
    for (int r = r0; r < r0 + 250; ++r) {
        float v = bf2f(xin[(size_t)r * 256 + t]);
        s += v; q += v * v;
    }
    atomicAdd(&bnsum[t], s);
    atomicAdd(&bnsq[t], q);
}

// ---------------- pooling: one block per group, binary search, no atomics ----------------
__global__ __launch_bounds__(512) void k_pool(const unsigned short* __restrict__ x1pre,
    const unsigned short* __restrict__ x2b, const int* __restrict__ batch,
    const float* __restrict__ bnsum, const float* __restrict__ bnsq,
    const float* __restrict__ gamma, const float* __restrict__ beta,
    float* __restrict__ out) {
    int g = blockIdx.x;
    __shared__ int sLo, sHi;
    if (threadIdx.x == 0) {
        int lo = 0, hi = NN;
        while (lo < hi) { int m = (lo + hi) >> 1; if (batch[m] < g) lo = m + 1; else hi = m; }
        sLo = lo;
    }
    if (threadIdx.x == 1) {
        int lo = 0, hi = NN;
        while (lo < hi) { int m = (lo + hi) >> 1; if (batch[m] < g + 1) lo = m + 1; else hi = m; }
        sHi = lo;
    }
    __syncthreads();
    int lo = sLo, hi = sHi, cnt = hi - lo;
    int t = threadIdx.x;
    bool first = t < 256;
    int f = first ? t : t - 256;
    const unsigned short* src = first ? x1pre : x2b;
    float sc = 1.f, sh = 0.f;
    if (first) {
        const float invN = 1.f / (float)NN;
        float mean = bnsum[f] * invN;
        float var  = bnsq[f] * invN - mean * mean;
        float istd = rsqrtf(var + BN_EPS);
        sc = gamma[f] * istd;
        sh = beta[f] - mean * sc;
    }
    float s = 0.f, mx = 0.f;
    int r = lo;
    for (; r + 1 < hi; r += 2) {
        float va = bf2f(src[(size_t)r * 256 + f]);
        float vb = bf2f(src[(size_t)(r + 1) * 256 + f]);
        if (first) {
            va = fmaxf(va * sc + sh, 0.f);
            vb = fmaxf(vb * sc + sh, 0.f);
        }
        s += va + vb;
        mx = fmaxf(mx, fmaxf(va, vb));
    }
    if (r < hi) {
        float va = bf2f(src[(size_t)r * 256 + f]);
        if (first) va = fmaxf(va * sc + sh, 0.f);
        s += va; mx = fmaxf(mx, va);
    }
    float mean = (cnt > 0) ? s / (float)cnt : 0.f;
    int off = first ? 0 : 256;
    out[g * 1024 + off + f] = mean;
    out[g * 1024 + 512 + off + f] = mx;
}

extern "C" void kernel_launch(void* const* d_in, const int* in_sizes, int n_in,
                              void* d_out, int out_size, void* d_ws, size_t ws_size,
                              hipStream_t stream) {
    const float* x     = (const float*)d_in[0];
    const int*   ei    = (const int*)d_in[1];
    const int*   batch = (const int*)d_in[2];
    const float* W1    = (const float*)d_in[3];
    const float* asrc1 = (const float*)d_in[4];
    const float* adst1 = (const float*)d_in[5];
    const float* b1    = (const float*)d_in[6];
    const float* gamma = (const float*)d_in[7];
    const float* beta  = (const float*)d_in[8];
    const float* W2    = (const float*)d_in[9];
    const float* asrc2 = (const float*)d_in[10];
    const float* adst2 = (const float*)d_in[11];
    const float* b2    = (const float*)d_in[12];
    float* out = (float*)d_out;

    char* p = (char*)d_ws;
    auto alloc = [&](size_t bytes) -> void* {
        void* r = (void*)p;
        p += (bytes + 255) & ~(size_t)255;
        return r;
    };
    unsigned short* hb    = (unsigned short*)alloc((size_t)NN * 256 * 2);
    unsigned short* x1pre = (unsigned short*)alloc((size_t)NN * 256 * 2);
    unsigned short* x2b   = (unsigned short*)alloc((size_t)NN * 256 * 2);
    unsigned short* W1t   = (unsigned short*)alloc((size_t)256 * 128 * 2);
    unsigned short* W2t   = (unsigned short*)alloc((size_t)256 * 256 * 2);
    float* alsrc = (float*)alloc((size_t)NN * 4 * 4);
    float* aldst = (float*)alloc((size_t)NN * 4 * 4);
    float* bnsum = (float*)alloc(256 * 4);
    float* bnsq  = (float*)alloc(256 * 4);       // contiguous with bnsum (one 2 KB memset)
    int*   cnt   = (int*)alloc((size_t)NN * 4);
    int*   colIdx = (int*)alloc((size_t)NN * ELLS * 4);   // ELL, 12.8 MB

    (void)hipMemsetAsync(bnsum, 0, 2 * 1024, stream);

    const int nGemm = 2 * ((NN + 127) / 128);     // 782
    const int nFill = (NE / 4 + 255) / 256;       // 782 blocks, 4 edges/thread

    // prep: W transposes + ELL self-loop/cnt init
    k_prep<<<384 + 196, 256, 0, stream>>>(W1, W1t, W2, W2t, cnt, colIdx);
    // standalone ELL edge fill (4-way ILP)
    k_fill<<<nFill, 256, 0, stream>>>(ei, cnt, colIdx);

    // layer 1
    k_gemm<0><<<nGemm, 256, 0, stream>>>(x, nullptr, W1t, hb, asrc1, adst1, alsrc, aldst,
                                         nullptr, nullptr, nullptr, nullptr, NN, 128);
    k_gat_agg<<<NN / 8, 256, 0, stream>>>(cnt, colIdx, alsrc, aldst, hb, b1, x1pre, 0, NN);
    k_bn_stats<<<200, 256, 0, stream>>>(x1pre, bnsum, bnsq);

    // layer 2
    k_gemm<1><<<nGemm, 256, 0, stream>>>(nullptr, x1pre, W2t, hb, asrc2, adst2, alsrc, aldst,
                                         bnsum, bnsq, gamma, beta, NN, 256);
    k_gat_agg<<<NN / 8, 256, 0, stream>>>(cnt, colIdx, alsrc, aldst, hb, b2, x2b, 1, NN);

    // pooling
    k_pool<<<NG, 512, 0, stream>>>(x1pre, x2b, batch, bnsum, bnsq, gamma, beta, out);
}

// Round 13
// 284.674 us; speedup vs baseline: 1.1183x; 1.0638x over previous
//
#include <hip/hip_runtime.h>
#include <hip/hip_bf16.h>
#include <hip/hip_fp16.h>
#include <math.h>

#define NN 50000
#define FIN 128
#define FH 256        // H*C = 256 output features per layer
#define NE 800000
#define NG 256
#define ELLS 64       // ELL row stride (max degree incl self loop; Poisson(16) => P(>63) ~ 1e-20)
#define NEG_SLOPE 0.2f
#define BN_EPS 1e-5f

typedef short bf16x8 __attribute__((ext_vector_type(8)));
typedef unsigned short u16x8 __attribute__((ext_vector_type(8)));
typedef unsigned long long u64x2 __attribute__((ext_vector_type(2)));
typedef float f32x4 __attribute__((ext_vector_type(4)));
typedef _Float16 f16x8 __attribute__((ext_vector_type(8)));

__device__ __forceinline__ float lrelu(float x) { return x > 0.f ? x : NEG_SLOPE * x; }
__device__ __forceinline__ float bf2f(unsigned short u) { return __uint_as_float(((unsigned int)u) << 16); }
__device__ __forceinline__ unsigned short f2bf(float f) {
    __hip_bfloat16 b = __float2bfloat16(f);
    return *reinterpret_cast<unsigned short*>(&b);
}
__device__ __forceinline__ unsigned short f2h(float f) {
    __half h = __float2half(f);
    return *reinterpret_cast<unsigned short*>(&h);
}
__device__ __forceinline__ float h2f(unsigned short u) {
    __half_raw r; r.x = u;
    return __half2float(__half(r));
}

// ---------------- prep: W transposes + ELL self-loop init, one launch ----------------
__global__ __launch_bounds__(256) void k_prep(const float* __restrict__ W1, unsigned short* __restrict__ W1t,
                                              const float* __restrict__ W2, unsigned short* __restrict__ W2t,
                                              int* __restrict__ cnt, int* __restrict__ colIdx) {
    int bid = blockIdx.x;
    if (bid < 384) {
        int o = bid * 256 + threadIdx.x;
        if (o < 256 * 128) {
            int c = o >> 7, k = o & 127;
            W1t[o] = f2bf(W1[(size_t)k * 256 + c]);
        } else {
            o -= 256 * 128;
            if (o < 256 * 256) {
                int c = o >> 8, k = o & 255;
                W2t[o] = f2bf(W2[(size_t)k * 256 + c]);
            }
        }
    } else {
        int i = (bid - 384) * 256 + threadIdx.x;
        if (i < NN) {
            cnt[i] = 1;
            colIdx[(size_t)i * ELLS] = i;   // self loop first
        }
    }
}

// ---------------- GEMM + fused attention logits + fused ELL fill tail (MODE 0) ----------------
// C[M,256](f16) = A[M,K] @ Bt[256,K]^T  (MFMA bf16, f32 accum, f16 output for packed gather)
// MODE 0: A f32; blocks [nGemm, nGemm+nFill) do ELL edge fill (4 edges/thread).
// MODE 1: A bf16 pre-BN, staging applies BN affine+relu.
template<int MODE>
__global__ __launch_bounds__(256) void k_gemm(const float* __restrict__ Af, const unsigned short* __restrict__ Ab,
                                              const unsigned short* __restrict__ Bt,
                                              unsigned short* __restrict__ C,
                                              const float* __restrict__ attS, const float* __restrict__ attD,
                                              float* __restrict__ alsrc, float* __restrict__ aldst,
                                              const float* __restrict__ bnsum, const float* __restrict__ bnsq,
                                              const float* __restrict__ gamma, const float* __restrict__ beta,
                                              const int* __restrict__ eiFill, int* __restrict__ cntFill,
                                              int* __restrict__ colIdxFill, int nGemm, int nFill,
                                              int M, int K) {
    __shared__ short lds[10240];                 // As(5120) + Bs(5120); reused as 64x138 C-stage
    __shared__ float sAs_[128], sAd_[128];
    __shared__ float s_scale[MODE == 1 ? 256 : 1];
    __shared__ float s_shift[MODE == 1 ? 256 : 1];
    short* As = lds;
    short* Bs = lds + 5120;

    int bid = blockIdx.x;
    if (MODE == 0 && bid >= nGemm) {
        int T = nFill * 256;
        int t = (bid - nGemm) * 256 + threadIdx.x;
        int e0 = t, e1 = t + T, e2 = t + 2 * T, e3 = t + 3 * T;
        int s0 = 0, s1 = 0, s2 = 0, s3 = 0, d0 = -1, d1 = -1, d2 = -1, d3 = -1;
        if (e0 < NE) { s0 = eiFill[e0]; d0 = eiFill[NE + e0]; }
        if (e1 < NE) { s1 = eiFill[e1]; d1 = eiFill[NE + e1]; }
        if (e2 < NE) { s2 = eiFill[e2]; d2 = eiFill[NE + e2]; }
        if (e3 < NE) { s3 = eiFill[e3]; d3 = eiFill[NE + e3]; }
        int p0 = 0, p1 = 0, p2 = 0, p3 = 0;
        if (d0 >= 0) p0 = atomicAdd(&cntFill[d0], 1);
        if (d1 >= 0) p1 = atomicAdd(&cntFill[d1], 1);
        if (d2 >= 0) p2 = atomicAdd(&cntFill[d2], 1);
        if (d3 >= 0) p3 = atomicAdd(&cntFill[d3], 1);
        if (d0 >= 0 && p0 < ELLS) colIdxFill[(size_t)d0 * ELLS + p0] = s0;
        if (d1 >= 0 && p1 < ELLS) colIdxFill[(size_t)d1 * ELLS + p1] = s1;
        if (d2 >= 0 && p2 < ELLS) colIdxFill[(size_t)d2 * ELLS + p2] = s2;
        if (d3 >= 0 && p3 < ELLS) colIdxFill[(size_t)d3 * ELLS + p3] = s3;
        return;
    }
    int tid = threadIdx.x;
    int lane = tid & 63, wid = tid >> 6;
    int wr = wid >> 1, wc = wid & 1;
    int row0 = (bid >> 1) * 128, col0 = (bid & 1) * 128;

    if (tid < 128) {
        sAs_[tid] = attS[col0 + tid];
        sAd_[tid] = attD[col0 + tid];
    }
    if (MODE == 1) {
        const float invN = 1.f / (float)NN;
        float mean = bnsum[tid] * invN;
        float var  = bnsq[tid] * invN - mean * mean;
        float istd = rsqrtf(var + BN_EPS);
        float sc = gamma[tid] * istd;
        s_scale[tid] = sc;
        s_shift[tid] = beta[tid] - mean * sc;
        __syncthreads();
    }
    f32x4 acc[4][4];
#pragma unroll
    for (int m = 0; m < 4; ++m)
#pragma unroll
        for (int n = 0; n < 4; ++n) acc[m][n] = (f32x4){0.f, 0.f, 0.f, 0.f};

    int r = tid >> 2, seg = tid & 3;
    int koff = (lane >> 4) * 8;

    float4 qa0[2], qa1[2];
    bf16x8 qab[2];
    bf16x8 qb[2];
    const float4 zf4 = make_float4(0.f, 0.f, 0.f, 0.f);
    const bf16x8 zb8 = {0, 0, 0, 0, 0, 0, 0, 0};

#pragma unroll
    for (int j = 0; j < 2; ++j) {
        int grow = row0 + r + j * 64;
        if (MODE == 0) {
            if (grow < M) {
                const float* ap = Af + (size_t)grow * K + seg * 8;
                qa0[j] = *(const float4*)ap;
                qa1[j] = *((const float4*)ap + 1);
            } else { qa0[j] = zf4; qa1[j] = zf4; }
        } else {
            qab[j] = (grow < M) ? *(const bf16x8*)(Ab + (size_t)grow * K + seg * 8) : zb8;
        }
        qb[j] = *(const bf16x8*)(Bt + (size_t)(col0 + r + j * 64) * K + seg * 8);
    }

    for (int k0 = 0; k0 < K; k0 += 32) {
#pragma unroll
        for (int j = 0; j < 2; ++j) {
            int row = r + j * 64;
            bf16x8 va;
            if (MODE == 0) {
                va[0] = (short)f2bf(qa0[j].x); va[1] = (short)f2bf(qa0[j].y);
                va[2] = (short)f2bf(qa0[j].z); va[3] = (short)f2bf(qa0[j].w);
                va[4] = (short)f2bf(qa1[j].x); va[5] = (short)f2bf(qa1[j].y);
                va[6] = (short)f2bf(qa1[j].z); va[7] = (short)f2bf(qa1[j].w);
            } else {
                int cb = k0 + seg * 8;
#pragma unroll
                for (int k = 0; k < 8; ++k) {
                    float f = bf2f((unsigned short)qab[j][k]) * s_scale[cb + k] + s_shift[cb + k];
                    va[k] = (short)f2bf(fmaxf(f, 0.f));
                }
            }
            *(bf16x8*)&As[row * 40 + seg * 8] = va;
            *(bf16x8*)&Bs[row * 40 + seg * 8] = qb[j];
        }
        __syncthreads();
        int kn = k0 + 32;
        if (kn < K) {
#pragma unroll
            for (int j = 0; j < 2; ++j) {
                int grow = row0 + r + j * 64;
                if (MODE == 0) {
                    if (grow < M) {
                        const float* ap = Af + (size_t)grow * K + kn + seg * 8;
                        qa0[j] = *(const float4*)ap;
                        qa1[j] = *((const float4*)ap + 1);
                    } else { qa0[j] = zf4; qa1[j] = zf4; }
                } else {
                    qab[j] = (grow < M) ? *(const bf16x8*)(Ab + (size_t)grow * K + kn + seg * 8) : zb8;
                }
                qb[j] = *(const bf16x8*)(Bt + (size_t)(col0 + r + j * 64) * K + kn + seg * 8);
            }
        }
        bf16x8 af[4], bfr[4];
#pragma unroll
        for (int m = 0; m < 4; ++m)
            af[m] = *(const bf16x8*)&As[(wr * 64 + m * 16 + (lane & 15)) * 40 + koff];
#pragma unroll
        for (int n = 0; n < 4; ++n)
            bfr[n] = *(const bf16x8*)&Bs[(wc * 64 + n * 16 + (lane & 15)) * 40 + koff];
#pragma unroll
        for (int m = 0; m < 4; ++m)
#pragma unroll
            for (int n = 0; n < 4; ++n)
                acc[m][n] = __builtin_amdgcn_mfma_f32_16x16x32_bf16(af[m], bfr[n], acc[m][n], 0, 0, 0);
        __syncthreads();
    }

    // ---- epilogue: stage C tile (f16) through LDS in two 64-row halves ----
    const int CST = 138;   // shorts; 64*138 = 8832 <= 10240
#pragma unroll 1
    for (int hh = 0; hh < 2; ++hh) {
        if (wr == hh) {
#pragma unroll
            for (int m = 0; m < 4; ++m) {
                int rl = m * 16 + (lane >> 4) * 4;
#pragma unroll
                for (int n = 0; n < 4; ++n) {
                    int cl = wc * 64 + n * 16 + (lane & 15);
#pragma unroll
                    for (int j = 0; j < 4; ++j)
                        lds[(rl + j) * CST + cl] = (short)f2h(acc[m][n][j]);
                }
            }
        }
        __syncthreads();
        int rl = tid >> 2, q = tid & 3;
        int grow = row0 + hh * 64 + rl;
        if (grow < M) {
            const short* cp = &lds[rl * CST + q * 32];
            bf16x8 v0 = *(const bf16x8*)(cp + 0);
            bf16x8 v1 = *(const bf16x8*)(cp + 8);
            bf16x8 v2 = *(const bf16x8*)(cp + 16);
            bf16x8 v3 = *(const bf16x8*)(cp + 24);
            unsigned short* op = C + (size_t)grow * 256 + col0 + q * 32;
            *(bf16x8*)(op + 0)  = v0;
            *(bf16x8*)(op + 8)  = v1;
            *(bf16x8*)(op + 16) = v2;
            *(bf16x8*)(op + 24) = v3;
            float ps = 0.f, pd = 0.f;
            const float* aS = &sAs_[q * 32];
            const float* aD = &sAd_[q * 32];
#pragma unroll
            for (int k = 0; k < 8; ++k) {
                float f0 = h2f((unsigned short)v0[k]);
                float f1 = h2f((unsigned short)v1[k]);
                float f2 = h2f((unsigned short)v2[k]);
                float f3 = h2f((unsigned short)v3[k]);
                ps += f0 * aS[k] + f1 * aS[k + 8] + f2 * aS[k + 16] + f3 * aS[k + 24];
                pd += f0 * aD[k] + f1 * aD[k + 8] + f2 * aD[k + 16] + f3 * aD[k + 24];
            }
            ps += __shfl_xor(ps, 1);
            pd += __shfl_xor(pd, 1);
            if ((q & 1) == 0) {
                int head = (col0 >> 6) + (q >> 1);
                alsrc[grow * 4 + head] = ps;
                aldst[grow * 4 + head] = pd;
            }
        }
        __syncthreads();
    }
}

// ---------------- GAT aggregation: 2 nodes/wave, ELL, f16 packed gather ----------------
__global__ __launch_bounds__(256) void k_gat_agg(const int* __restrict__ cnt, const int* __restrict__ colIdx,
    const float* __restrict__ alsrc, const float* __restrict__ aldst, const unsigned short* __restrict__ h,
    const float* __restrict__ bias, unsigned short* __restrict__ outb, int relu_nt, int n) {
    __shared__ float ex_s[4][2][32][4];
    __shared__ int   src_s[4][2][32];
    int wave = threadIdx.x >> 6, lane = threadIdx.x & 63;
    int half = lane >> 5, hlane = lane & 31;
    int node = blockIdx.x * 8 + wave * 2 + half;   // grid = NN/8 exactly
    int deg = min(cnt[node], ELLS);
    const int* crow = colIdx + (size_t)node * ELLS;
    int hf = hlane >> 3;
    float4 ad = *(const float4*)(aldst + (size_t)node * 4);
    float m0 = -1e30f, m1 = -1e30f, m2 = -1e30f, m3 = -1e30f;
    float d0 = 0.f, d1 = 0.f, d2 = 0.f, d3 = 0.f;
    f16x8 accv = {0, 0, 0, 0, 0, 0, 0, 0};

    for (int base = 0; base < deg; base += 32) {
        int cnt32 = min(32, deg - base);
        int src = node;
        float e0 = -1e30f, e1 = -1e30f, e2 = -1e30f, e3 = -1e30f;
        if (hlane < cnt32) {
            src = crow[base + hlane];
            float4 as = *(const float4*)(alsrc + (size_t)src * 4);
            e0 = lrelu(as.x + ad.x);
            e1 = lrelu(as.y + ad.y);
            e2 = lrelu(as.z + ad.z);
            e3 = lrelu(as.w + ad.w);
        }
        float c0 = e0, c1 = e1, c2 = e2, c3 = e3;
#pragma unroll
        for (int off = 16; off > 0; off >>= 1) {
            c0 = fmaxf(c0, __shfl_xor(c0, off));
            c1 = fmaxf(c1, __shfl_xor(c1, off));
            c2 = fmaxf(c2, __shfl_xor(c2, off));
            c3 = fmaxf(c3, __shfl_xor(c3, off));
        }
        float nm0 = fmaxf(m0, c0), nm1 = fmaxf(m1, c1), nm2 = fmaxf(m2, c2), nm3 = fmaxf(m3, c3);
        float sc0 = __expf(m0 - nm0), sc1 = __expf(m1 - nm1), sc2 = __expf(m2 - nm2), sc3 = __expf(m3 - nm3);
        float x0 = __expf(e0 - nm0), x1 = __expf(e1 - nm1), x2 = __expf(e2 - nm2), x3 = __expf(e3 - nm3);
        float s0 = x0, s1 = x1, s2 = x2, s3 = x3;
#pragma unroll
        for (int off = 16; off > 0; off >>= 1) {
            s0 += __shfl_xor(s0, off);
            s1 += __shfl_xor(s1, off);
            s2 += __shfl_xor(s2, off);
            s3 += __shfl_xor(s3, off);
        }
        d0 = d0 * sc0 + s0; d1 = d1 * sc1 + s1; d2 = d2 * sc2 + s2; d3 = d3 * sc3 + s3;
        m0 = nm0; m1 = nm1; m2 = nm2; m3 = nm3;
        float scl = (hf == 0) ? sc0 : (hf == 1) ? sc1 : (hf == 2) ? sc2 : sc3;
        {
            _Float16 sh = (_Float16)scl;
            f16x8 sv = {sh, sh, sh, sh, sh, sh, sh, sh};
            accv *= sv;
        }
        ex_s[wave][half][hlane][0] = x0; ex_s[wave][half][hlane][1] = x1;
        ex_s[wave][half][hlane][2] = x2; ex_s[wave][half][hlane][3] = x3;
        src_s[wave][half][hlane] = src;
        // ---- phase B: packed f16 gather, 2 edges in flight per half ----
        for (int j = 0; j < cnt32; j += 2) {
            float w0 = ex_s[wave][half][j][hf];
            f16x8 h0 = *(const f16x8*)(h + (size_t)src_s[wave][half][j] * 256 + hlane * 8);
            float w1 = 0.f;
            f16x8 h1 = {0, 0, 0, 0, 0, 0, 0, 0};
            if (j + 1 < cnt32) {
                w1 = ex_s[wave][half][j + 1][hf];
                h1 = *(const f16x8*)(h + (size_t)src_s[wave][half][j + 1] * 256 + hlane * 8);
            }
            _Float16 w0h = (_Float16)w0, w1h = (_Float16)w1;
            f16x8 w0v = {w0h, w0h, w0h, w0h, w0h, w0h, w0h, w0h};
            f16x8 w1v = {w1h, w1h, w1h, w1h, w1h, w1h, w1h, w1h};
            accv += h0 * w0v;
            accv += h1 * w1v;
        }
    }

    float dd = (hf == 0) ? d0 : (hf == 1) ? d1 : (hf == 2) ? d2 : d3;
    float inv = 1.f / (dd + 1e-16f);
    float4 b0 = *(const float4*)(bias + hlane * 8);
    float4 b1 = *(const float4*)(bias + hlane * 8 + 4);
    float o[8];
    o[0] = (float)accv[0] * inv + b0.x; o[1] = (float)accv[1] * inv + b0.y;
    o[2] = (float)accv[2] * inv + b0.z; o[3] = (float)accv[3] * inv + b0.w;
    o[4] = (float)accv[4] * inv + b1.x; o[5] = (float)accv[5] * inv + b1.y;
    o[6] = (float)accv[6] * inv + b1.z; o[7] = (float)accv[7] * inv + b1.w;
    u16x8 ob;
    if (relu_nt) {
#pragma unroll
        for (int k = 0; k < 8; ++k) ob[k] = f2bf(fmaxf(o[k], 0.f));
        u64x2 w = *(u64x2*)&ob;
        __builtin_nontemporal_store(w, (u64x2*)(outb + (size_t)node * 256 + hlane * 8));
    } else {
#pragma unroll
        for (int k = 0; k < 8; ++k) ob[k] = f2bf(o[k]);
        *(u64x2*)(outb + (size_t)node * 256 + hlane * 8) = *(u64x2*)&ob;
    }
}

// ---------------- BatchNorm stats: vectorized (short8 loads, LDS reduce) ----------------
__global__ __launch_bounds__(256) void k_bn_stats(const unsigned short* __restrict__ xin, float* bnsum, float* bnsq) {
    __shared__ float ls[8][256], lq[8][256];
    int t = threadIdx.x, cg = t & 31, rg = t >> 5;
    int r0 = blockIdx.x * 200;               // 250 blocks x 200 rows
    float s[8], q[8];
#pragma unroll
    for (int k = 0; k < 8; ++k) { s[k] = 0.f; q[k] = 0.f; }
    for (int r = r0 + rg; r < r0 + 200; r += 8) {
        u16x8 v = *(const u16x8*)(xin + (size_t)r * 256 + cg * 8);
#pragma unroll
        for (int k = 0; k < 8; ++k) {
            float f = bf2f(v[k]);
            s[k] += f; q[k] += f * f;
        }
    }
#pragma unroll
    for (int k = 0; k < 8; ++k) { ls[rg][cg * 8 + k] = s[k]; lq[rg][cg * 8 + k] = q[k]; }
    __syncthreads();
    float S = 0.f, Q = 0.f;
#pragma unroll
    for (int j = 0; j < 8; ++j) { S += ls[j][t]; Q += lq[j][t]; }
    atomicAdd(&bnsum[t], S);
    atomicAdd(&bnsq[t], Q);
}

// ---------------- pooling: one block per group, binary search, no atomics ----------------
__global__ __launch_bounds__(512) void k_pool(const unsigned short* __restrict__ x1pre,
    const unsigned short* __restrict__ x2b, const int* __restrict__ batch,
    const float* __restrict__ bnsum, const float* __restrict__ bnsq,
    const float* __restrict__ gamma, const float* __restrict__ beta,
    float* __restrict__ out) {
    int g = blockIdx.x;
    __shared__ int sLo, sHi;
    if (threadIdx.x == 0) {
        int lo = 0, hi = NN;
        while (lo < hi) { int m = (lo + hi) >> 1; if (batch[m] < g) lo = m + 1; else hi = m; }
        sLo = lo;
    }
    if (threadIdx.x == 1) {
        int lo = 0, hi = NN;
        while (lo < hi) { int m = (lo + hi) >> 1; if (batch[m] < g + 1) lo = m + 1; else hi = m; }
        sHi = lo;
    }
    __syncthreads();
    int lo = sLo, hi = sHi, cnt = hi - lo;
    int t = threadIdx.x;
    bool first = t < 256;
    int f = first ? t : t - 256;
    const unsigned short* src = first ? x1pre : x2b;
    float sc = 1.f, sh = 0.f;
    if (first) {
        const float invN = 1.f / (float)NN;
        float mean = bnsum[f] * invN;
        float var  = bnsq[f] * invN - mean * mean;
        float istd = rsqrtf(var + BN_EPS);
        sc = gamma[f] * istd;
        sh = beta[f] - mean * sc;
    }
    float s = 0.f, mx = 0.f;
    int r = lo;
    for (; r + 1 < hi; r += 2) {
        float va = bf2f(src[(size_t)r * 256 + f]);
        float vb = bf2f(src[(size_t)(r + 1) * 256 + f]);
        if (first) {
            va = fmaxf(va * sc + sh, 0.f);
            vb = fmaxf(vb * sc + sh, 0.f);
        }
        s += va + vb;
        mx = fmaxf(mx, fmaxf(va, vb));
    }
    if (r < hi) {
        float va = bf2f(src[(size_t)r * 256 + f]);
        if (first) va = fmaxf(va * sc + sh, 0.f);
        s += va; mx = fmaxf(mx, va);
    }
    float mean = (cnt > 0) ? s / (float)cnt : 0.f;
    int off = first ? 0 : 256;
    out[g * 1024 + off + f] = mean;
    out[g * 1024 + 512 + off + f] = mx;
}

extern "C" void kernel_launch(void* const* d_in, const int* in_sizes, int n_in,
                              void* d_out, int out_size, void* d_ws, size_t ws_size,
                              hipStream_t stream) {
    const float* x     = (const float*)d_in[0];
    const int*   ei    = (const int*)d_in[1];
    const int*   batch = (const int*)d_in[2];
    const float* W1    = (const float*)d_in[3];
    const float* asrc1 = (const float*)d_in[4];
    const float* adst1 = (const float*)d_in[5];
    const float* b1    = (const float*)d_in[6];
    const float* gamma = (const float*)d_in[7];
    const float* beta  = (const float*)d_in[8];
    const float* W2    = (const float*)d_in[9];
    const float* asrc2 = (const float*)d_in[10];
    const float* adst2 = (const float*)d_in[11];
    const float* b2    = (const float*)d_in[12];
    float* out = (float*)d_out;

    char* p = (char*)d_ws;
    auto alloc = [&](size_t bytes) -> void* {
        void* r = (void*)p;
        p += (bytes + 255) & ~(size_t)255;
        return r;
    };
    unsigned short* hb    = (unsigned short*)alloc((size_t)NN * 256 * 2);   // layer features, f16
    unsigned short* x1pre = (unsigned short*)alloc((size_t)NN * 256 * 2);   // pre-BN layer1 out, bf16
    unsigned short* x2b   = (unsigned short*)alloc((size_t)NN * 256 * 2);   // layer-2 output, bf16
    unsigned short* W1t   = (unsigned short*)alloc((size_t)256 * 128 * 2);
    unsigned short* W2t   = (unsigned short*)alloc((size_t)256 * 256 * 2);
    float* alsrc = (float*)alloc((size_t)NN * 4 * 4);
    float* aldst = (float*)alloc((size_t)NN * 4 * 4);
    float* bnsum = (float*)alloc(256 * 4);
    float* bnsq  = (float*)alloc(256 * 4);       // contiguous with bnsum (one 2 KB memset)
    int*   cnt   = (int*)alloc((size_t)NN * 4);
    int*   colIdx = (int*)alloc((size_t)NN * ELLS * 4);   // ELL, 12.8 MB

    (void)hipMemsetAsync(bnsum, 0, 2 * 1024, stream);

    const int nGemm = 2 * ((NN + 127) / 128);     // 782
    const int nFill = (NE / 4 + 255) / 256;       // 782 fill blocks, 4 edges/thread

    // prep: W transposes + ELL self-loop/cnt init
    k_prep<<<384 + 196, 256, 0, stream>>>(W1, W1t, W2, W2t, cnt, colIdx);

    // layer 1: GEMM blocks first, fill tail overlaps
    k_gemm<0><<<nGemm + nFill, 256, 0, stream>>>(x, nullptr, W1t, hb, asrc1, adst1, alsrc, aldst,
                                                 nullptr, nullptr, nullptr, nullptr,
                                                 ei, cnt, colIdx, nGemm, nFill, NN, 128);
    k_gat_agg<<<NN / 8, 256, 0, stream>>>(cnt, colIdx, alsrc, aldst, hb, b1, x1pre, 0, NN);
    k_bn_stats<<<250, 256, 0, stream>>>(x1pre, bnsum, bnsq);

    // layer 2
    k_gemm<1><<<nGemm, 256, 0, stream>>>(nullptr, x1pre, W2t, hb, asrc2, adst2, alsrc, aldst,
                                         bnsum, bnsq, gamma, beta,
                                         nullptr, nullptr, nullptr, nGemm, 0, NN, 256);
    k_gat_agg<<<NN / 8, 256, 0, stream>>>(cnt, colIdx, alsrc, aldst, hb, b2, x2b, 1, NN);

    // pooling
    k_pool<<<NG, 512, 0, stream>>>(x1pre, x2b, batch, bnsum, bnsq, gamma, beta, out);
}